// Round 2
// baseline (177.393 us; speedup 1.0000x reference)
//
#include <hip/hip_runtime.h>
#include <hip/hip_bf16.h>

// ---------------------------------------------------------------------------
// LocalAttention R13:
//  - qkv_k: REVERTED to the R2 interior (583 TF / 44.2us verified). R12's
//    256^2 8-phase lost: 192 blocks -> 1 block/CU on 256 CUs = 75% machine,
//    shallow K=1024 can't amortize the deep prologue. Evidence: R12 total
//    176.8 vs 172.2 (qkv ~49us).
//  - wo_k: widened verified swapped/float4 structure 128x64 -> 128x128.
//    grid 8x32=256 blocks = exactly full CU coverage, half the barriers,
//    half the A re-reads. Predict ~22 -> ~15us.
//  - attn_k: double-buffered Ks/Vt, prefetch next tile (K gload_lds + V->reg)
//    issued right after QK^T, V transpose-write after PV (T14), ONE barrier
//    per iteration, setprio(1) around MFMA clusters (T5). Predict ~12 -> ~9us.
// Fixed costs: ~86us of harness poison fills (2 per iter) in dur_us.
// ---------------------------------------------------------------------------

typedef __attribute__((ext_vector_type(8))) short bf16x8;
typedef __attribute__((ext_vector_type(4))) float f32x4;

#define S_LEN 4096
#define D_MODEL 1024
#define N_HEADS 16
#define HEAD_DIM 64
#define WINDOW 256
#define QKV_LD 3072

static __device__ __forceinline__ unsigned short f2bfbits(float f) {
    __hip_bfloat16 h = __float2bfloat16(f);
    unsigned short u;
    __builtin_memcpy(&u, &h, sizeof(u));
    return u;
}

typedef const __attribute__((address_space(1))) void c_gvoid;
typedef __attribute__((address_space(3))) void lvoid;
static __device__ __forceinline__ void gload16(const void* g, void* l) {
    __builtin_amdgcn_global_load_lds((c_gvoid*)g, (lvoid*)l, 16, 0, 0);
}

// ---------------- fused prep: x-cast, W transposes, bias concat (R8) --------
__global__ __launch_bounds__(256) void prep_k(const float* __restrict__ x,
                                              const float* __restrict__ Wq,
                                              const float* __restrict__ Wk,
                                              const float* __restrict__ Wv,
                                              const float* __restrict__ Wo,
                                              const float* __restrict__ bq,
                                              const float* __restrict__ bk,
                                              const float* __restrict__ bv,
                                              unsigned short* __restrict__ xb,
                                              __hip_bfloat16* __restrict__ Wqkvt,
                                              __hip_bfloat16* __restrict__ Wot,
                                              float* __restrict__ bias_cat) {
    const int b = blockIdx.x;
    const int t = threadIdx.x;
    if (b < 2048) {
        int i = b * 2048 + t * 8;
        float4 v0 = *(const float4*)(x + i);
        float4 v1 = *(const float4*)(x + i + 4);
        ushort4 o0, o1;
        o0.x = f2bfbits(v0.x); o0.y = f2bfbits(v0.y);
        o0.z = f2bfbits(v0.z); o0.w = f2bfbits(v0.w);
        o1.x = f2bfbits(v1.x); o1.y = f2bfbits(v1.y);
        o1.z = f2bfbits(v1.z); o1.w = f2bfbits(v1.w);
        *(ushort4*)(xb + i) = o0;
        *(ushort4*)(xb + i + 4) = o1;
        return;
    }
    if (b < 3072) {
        __shared__ __hip_bfloat16 tile[64][65];
        const int m = (b - 2048) >> 8;
        const int tid = (b - 2048) & 255;
        const int n0 = (tid & 15) * 64, k0 = (tid >> 4) * 64;
        const float* src = (m == 0) ? Wq : (m == 1) ? Wk : (m == 2) ? Wv : Wo;
        __hip_bfloat16* dst = (m < 3) ? (Wqkvt + (size_t)m * D_MODEL * D_MODEL) : Wot;
        for (int c = t; c < 1024; c += 256) {
            int r = c >> 4, c4 = (c & 15) * 4;
            float4 v = *(const float4*)(src + (size_t)(k0 + r) * D_MODEL + n0 + c4);
            tile[r][c4 + 0] = __float2bfloat16(v.x);
            tile[r][c4 + 1] = __float2bfloat16(v.y);
            tile[r][c4 + 2] = __float2bfloat16(v.z);
            tile[r][c4 + 3] = __float2bfloat16(v.w);
        }
        __syncthreads();
        for (int c = t; c < 1024; c += 256) {
            int rr = c >> 4, c4 = (c & 15) * 4;
            ushort4 o;
            unsigned short u0, u1, u2, u3;
            __builtin_memcpy(&u0, &tile[c4 + 0][rr], 2);
            __builtin_memcpy(&u1, &tile[c4 + 1][rr], 2);
            __builtin_memcpy(&u2, &tile[c4 + 2][rr], 2);
            __builtin_memcpy(&u3, &tile[c4 + 3][rr], 2);
            o.x = u0; o.y = u1; o.z = u2; o.w = u3;
            *(ushort4*)((unsigned short*)dst + (size_t)(n0 + rr) * D_MODEL + k0 + c4) = o;
        }
        return;
    }
    for (int c = t; c < 3 * D_MODEL; c += 256) {
        float v = (c < 1024) ? bq[c] : (c < 2048) ? bk[c - 1024] : bv[c - 2048];
        bias_cat[c] = v;
    }
}

// ---------------- QKV GEMM: exact R2 interior (measured 44.2us) -------------
// C[4096][3072] = xb[4096][1024] * Wqkvt[3072][1024]^T + bcat. 128x128, BK=32.
__global__ __launch_bounds__(256) void qkv_k(const __hip_bfloat16* __restrict__ A,
                                             const __hip_bfloat16* __restrict__ Bt,
                                             const float* __restrict__ bias,
                                             __hip_bfloat16* __restrict__ Cout) {
    constexpr int K = D_MODEL, N = QKV_LD;
    __shared__ __align__(16) __hip_bfloat16 As[128 * 32];
    __shared__ __align__(16) __hip_bfloat16 Bs[128 * 32];

    const int m0 = blockIdx.y * 128, n0 = blockIdx.x * 128;
    const int t = threadIdx.x;
    const int wave = t >> 6, lane = t & 63;
    const int quad = lane >> 4, l16 = lane & 15;
    const int wm = (wave & 1) * 64, wn = (wave >> 1) * 64;

    const int srow = t >> 2;           // 0..63
    const int scol = (t & 3) * 8;      // 0,8,16,24

    f32x4 acc[4][4];
#pragma unroll
    for (int mi = 0; mi < 4; ++mi)
#pragma unroll
        for (int ni = 0; ni < 4; ++ni) acc[mi][ni] = (f32x4){0.f, 0.f, 0.f, 0.f};

    const __hip_bfloat16* gA = A + (size_t)(m0 + srow) * K + scol;
    const __hip_bfloat16* gB = Bt + (size_t)(n0 + srow) * K + scol;
    const size_t strideA = (size_t)64 * K;

    for (int k0 = 0; k0 < K; k0 += 32) {
        gload16(gA + k0, &As[t * 8]);
        gload16(gA + k0 + strideA, &As[2048 + t * 8]);
        gload16(gB + k0, &Bs[t * 8]);
        gload16(gB + k0 + strideA, &Bs[2048 + t * 8]);
        __syncthreads();

        bf16x8 af[4], bfr[4];
#pragma unroll
        for (int mi = 0; mi < 4; ++mi)
            af[mi] = *(const bf16x8*)&As[(wm + mi * 16 + l16) * 32 + quad * 8];
#pragma unroll
        for (int ni = 0; ni < 4; ++ni)
            bfr[ni] = *(const bf16x8*)&Bs[(wn + ni * 16 + l16) * 32 + quad * 8];
#pragma unroll
        for (int mi = 0; mi < 4; ++mi)
#pragma unroll
            for (int ni = 0; ni < 4; ++ni)
                acc[mi][ni] = __builtin_amdgcn_mfma_f32_16x16x32_bf16(
                    af[mi], bfr[ni], acc[mi][ni], 0, 0, 0);
        __syncthreads();
    }

    // R2 epilogue: C row = quad*4+r, col = l16 (per 16x16 frag)
#pragma unroll
    for (int mi = 0; mi < 4; ++mi) {
#pragma unroll
        for (int ni = 0; ni < 4; ++ni) {
#pragma unroll
            for (int r = 0; r < 4; ++r) {
                int row = m0 + wm + mi * 16 + quad * 4 + r;
                int col = n0 + wn + ni * 16 + l16;
                float v = acc[mi][ni][r] + bias[col];
                Cout[(size_t)row * N + col] = __float2bfloat16(v);
            }
        }
    }
}

// ---------------- Wo GEMM: swapped/float4, widened to 128x128 (R13) ---------
__global__ __launch_bounds__(256) void wo_k(const __hip_bfloat16* __restrict__ A,
                                            const __hip_bfloat16* __restrict__ Bt,
                                            const float* __restrict__ bias,
                                            float* __restrict__ Cout) {
    constexpr int TM = 128, TN = 128, K = D_MODEL, N = D_MODEL;
    constexpr int MI = 4, NI = 4;
    __shared__ __align__(16) __hip_bfloat16 As[TM * 32];
    __shared__ __align__(16) __hip_bfloat16 Bs[TN * 32];

    const int m0 = blockIdx.y * TM, n0 = blockIdx.x * TN;
    const int t = threadIdx.x;
    const int wave = t >> 6, lane = t & 63;
    const int quad = lane >> 4, l16 = lane & 15;
    const int wm = (wave & 1) * 64, wn = (wave >> 1) * 64;

    const int srow = t >> 2;
    const int scol = (t & 3) * 8;

    f32x4 acc[MI][NI];
#pragma unroll
    for (int mi = 0; mi < MI; ++mi)
#pragma unroll
        for (int ni = 0; ni < NI; ++ni) acc[mi][ni] = (f32x4){0.f, 0.f, 0.f, 0.f};

    const __hip_bfloat16* gA = A + (size_t)(m0 + srow) * K + scol;
    const __hip_bfloat16* gB = Bt + (size_t)(n0 + srow) * K + scol;
    const size_t stride64 = (size_t)64 * K;

    for (int k0 = 0; k0 < K; k0 += 32) {
        gload16(gA + k0, &As[t * 8]);
        gload16(gA + k0 + stride64, &As[2048 + t * 8]);
        gload16(gB + k0, &Bs[t * 8]);
        gload16(gB + k0 + stride64, &Bs[2048 + t * 8]);
        __syncthreads();

        bf16x8 af[MI], bfr[NI];
#pragma unroll
        for (int mi = 0; mi < MI; ++mi)
            af[mi] = *(const bf16x8*)&As[(wm + mi * 16 + l16) * 32 + quad * 8];
#pragma unroll
        for (int ni = 0; ni < NI; ++ni)
            bfr[ni] = *(const bf16x8*)&Bs[(wn + ni * 16 + l16) * 32 + quad * 8];
#pragma unroll
        for (int mi = 0; mi < MI; ++mi)
#pragma unroll
            for (int ni = 0; ni < NI; ++ni)
                acc[mi][ni] = __builtin_amdgcn_mfma_f32_16x16x32_bf16(
                    bfr[ni], af[mi], acc[mi][ni], 0, 0, 0);
        __syncthreads();
    }

    float4 bv[NI];
#pragma unroll
    for (int ni = 0; ni < NI; ++ni)
        bv[ni] = *(const float4*)&bias[n0 + wn + ni * 16 + quad * 4];
#pragma unroll
    for (int mi = 0; mi < MI; ++mi) {
        const int row = m0 + wm + mi * 16 + l16;
#pragma unroll
        for (int ni = 0; ni < NI; ++ni) {
            const int col = n0 + wn + ni * 16 + quad * 4;
            float4 o;
            o.x = acc[mi][ni][0] + bv[ni].x;
            o.y = acc[mi][ni][1] + bv[ni].y;
            o.z = acc[mi][ni][2] + bv[ni].z;
            o.w = acc[mi][ni][3] + bv[ni].w;
            *(float4*)(Cout + (size_t)row * N + col) = o;
        }
    }
}

// ---------------- sliding-window flash attention, 128-q blocks (R13) --------
// Double-buffered K/V, prefetch issued after QK^T (T14), one barrier/iter,
// setprio around MFMA clusters (T5). Numerics identical to R8 attn.
__global__ __launch_bounds__(256) void attn_k(const __hip_bfloat16* __restrict__ QKV,
                                              __hip_bfloat16* __restrict__ AO) {
    __shared__ __align__(16) __hip_bfloat16 Qs[128 * 64];     // 16 KB
    __shared__ __align__(16) __hip_bfloat16 Ks[2][64 * 64];   // 16 KB
    __shared__ __align__(16) __hip_bfloat16 Vt[2][64 * 72];   // 18 KB
    __shared__ __align__(16) __hip_bfloat16 Ps[128 * 72];     // 18 KB

    const int h = blockIdx.y;
    const int i0 = blockIdx.x * 128;
    const int t = threadIdx.x;
    const int wave = t >> 6, lane = t & 63;
    const int quad = lane >> 4, l16 = lane & 15;
    const float sc = 0.125f * 1.44269504088896f;  // 1/sqrt(64) * log2(e)

    const __hip_bfloat16* Q = QKV + h * HEAD_DIM;
    const __hip_bfloat16* K = QKV + D_MODEL + h * HEAD_DIM;
    const __hip_bfloat16* V = QKV + 2 * D_MODEL + h * HEAD_DIM;

    const int grow = t >> 3;                       // 0..31
    const int glog = ((t & 7) ^ ((t >> 3) & 7)) * 8;
    const int vp = t >> 3, vc = t & 7;

    const int tt0 = (i0 >= WINDOW) ? 0 : ((WINDOW - i0) >> 6);

    // ---- prologue: stage Q + first K/V tile (buf 0), single barrier --------
#pragma unroll
    for (int p = 0; p < 4; ++p)
        gload16(Q + (size_t)(i0 + p * 32 + grow) * QKV_LD + glog,
                &Qs[p * 2048 + t * 8]);
    {
        const int tb0 = i0 - WINDOW + tt0 * 64;
        uint4 pv0 = *(const uint4*)(V + (size_t)(tb0 + 2 * vp) * QKV_LD + vc * 8);
        uint4 pv1 = *(const uint4*)(V + (size_t)(tb0 + 2 * vp + 1) * QKV_LD + vc * 8);
#pragma unroll
        for (int p = 0; p < 2; ++p)
            gload16(K + (size_t)(tb0 + p * 32 + grow) * QKV_LD + glog,
                    &Ks[0][p * 2048 + t * 8]);
        const unsigned short* a0 = (const unsigned short*)&pv0;
        const unsigned short* a1 = (const unsigned short*)&pv1;
#pragma unroll
        for (int j = 0; j < 8; ++j) {
            unsigned int pk = (unsigned int)a0[j] | ((unsigned int)a1[j] << 16);
            *(unsigned int*)&Vt[0][(vc * 8 + j) * 72 + 2 * vp] = pk;
        }
    }
    __syncthreads();

    const int rq0 = wave * 32 + l16;     // lane's two q rows: rq0, rq0+16
    bf16x8 aq[2][2];
#pragma unroll
    for (int m = 0; m < 2; ++m) {
        const int rq = rq0 + m * 16;
#pragma unroll
        for (int kk = 0; kk < 2; ++kk)
            aq[m][kk] = *(const bf16x8*)&Qs[rq * 64 + ((kk * 4 + quad) ^ (rq & 7)) * 8];
    }

    float m_i[2] = {-3.0e38f, -3.0e38f}, l_i[2] = {0.f, 0.f};
    f32x4 Ov[2][4];
#pragma unroll
    for (int m = 0; m < 2; ++m)
#pragma unroll
        for (int no = 0; no < 4; ++no) Ov[m][no] = (f32x4){0.f, 0.f, 0.f, 0.f};

    for (int tt = tt0; tt < 6; ++tt) {
        const int tb = i0 - WINDOW + tt * 64;
        const int buf = (tt - tt0) & 1;

        // ---- QK^T on Ks[buf] ----
        f32x4 s[2][4];
#pragma unroll
        for (int m = 0; m < 2; ++m)
#pragma unroll
            for (int ni = 0; ni < 4; ++ni) s[m][ni] = (f32x4){0.f, 0.f, 0.f, 0.f};
        __builtin_amdgcn_s_setprio(1);
#pragma unroll
        for (int kk = 0; kk < 2; ++kk)
#pragma unroll
            for (int ni = 0; ni < 4; ++ni) {
                int rk = ni * 16 + l16;
                bf16x8 bk = *(const bf16x8*)&Ks[buf][rk * 64 + ((kk * 4 + quad) ^ (rk & 7)) * 8];
#pragma unroll
                for (int m = 0; m < 2; ++m)
                    s[m][ni] = __builtin_amdgcn_mfma_f32_16x16x32_bf16(
                        bk, aq[m][kk], s[m][ni], 0, 0, 0);
            }
        __builtin_amdgcn_s_setprio(0);

        // ---- prefetch next tile: V -> regs, K -> Ks[buf^1] (issue early) ---
        const bool pf = (tt < 5);
        uint4 nv0, nv1;
        if (pf) {
            const int tbn = tb + 64;
            nv0 = *(const uint4*)(V + (size_t)(tbn + 2 * vp) * QKV_LD + vc * 8);
            nv1 = *(const uint4*)(V + (size_t)(tbn + 2 * vp + 1) * QKV_LD + vc * 8);
#pragma unroll
            for (int p = 0; p < 2; ++p)
                gload16(K + (size_t)(tbn + p * 32 + grow) * QKV_LD + glog,
                        &Ks[buf ^ 1][p * 2048 + t * 8]);
        }

        // ---- softmax (unchanged numerics) ----
#pragma unroll
        for (int m = 0; m < 2; ++m) {
            const int qi = i0 + rq0 + m * 16;
            float mx = -3.0e38f;
#pragma unroll
            for (int ni = 0; ni < 4; ++ni)
#pragma unroll
                for (int r = 0; r < 4; ++r) {
                    int j = tb + ni * 16 + quad * 4 + r;
                    float v = s[m][ni][r] * sc;
                    bool ok = (j <= qi) && (qi - j < WINDOW);
                    v = ok ? v : -3.0e38f;
                    s[m][ni][r] = v;
                    mx = fmaxf(mx, v);
                }
            mx = fmaxf(mx, __shfl_xor(mx, 16));
            mx = fmaxf(mx, __shfl_xor(mx, 32));
            const float mn = fmaxf(m_i[m], mx);
            const float alpha = exp2f(m_i[m] - mn);
            m_i[m] = mn;
            float sum = 0.f;
#pragma unroll
            for (int ni = 0; ni < 4; ++ni)
#pragma unroll
                for (int r = 0; r < 4; ++r) {
                    float e = exp2f(s[m][ni][r] - mn);
                    s[m][ni][r] = e;
                    sum += e;
                }
            sum += __shfl_xor(sum, 16);
            sum += __shfl_xor(sum, 32);
            l_i[m] = l_i[m] * alpha + sum;
#pragma unroll
            for (int no = 0; no < 4; ++no) Ov[m][no] *= alpha;

            const int rq = rq0 + m * 16;
#pragma unroll
            for (int ni = 0; ni < 4; ++ni) {
                ushort4 w4;
                w4.x = f2bfbits(s[m][ni][0]); w4.y = f2bfbits(s[m][ni][1]);
                w4.z = f2bfbits(s[m][ni][2]); w4.w = f2bfbits(s[m][ni][3]);
                *(ushort4*)&Ps[rq * 72 + ni * 16 + quad * 4] = w4;
            }
        }

        // ---- PV on Vt[buf] ----
        __builtin_amdgcn_s_setprio(1);
#pragma unroll
        for (int kk = 0; kk < 2; ++kk) {
            bf16x8 ap[2];
#pragma unroll
            for (int m = 0; m < 2; ++m)
                ap[m] = *(const bf16x8*)&Ps[(rq0 + m * 16) * 72 + kk * 32 + quad * 8];
#pragma unroll
            for (int no = 0; no < 4; ++no) {
                bf16x8 bvv = *(const bf16x8*)&Vt[buf][(no * 16 + l16) * 72 + kk * 32 + quad * 8];
#pragma unroll
                for (int m = 0; m < 2; ++m)
                    Ov[m][no] = __builtin_amdgcn_mfma_f32_16x16x32_bf16(
                        bvv, ap[m], Ov[m][no], 0, 0, 0);
            }
        }
        __builtin_amdgcn_s_setprio(0);

        // ---- write prefetched V into Vt[buf^1] (loads have had QK^T..PV to
        //      return; compiler inserts the exact vmcnt wait) ----
        if (pf) {
            const unsigned short* a0 = (const unsigned short*)&nv0;
            const unsigned short* a1 = (const unsigned short*)&nv1;
#pragma unroll
            for (int j = 0; j < 8; ++j) {
                unsigned int pk = (unsigned int)a0[j] | ((unsigned int)a1[j] << 16);
                *(unsigned int*)&Vt[buf ^ 1][(vc * 8 + j) * 72 + 2 * vp] = pk;
            }
        }
        __syncthreads();  // drains K gload_lds; next iter reads Ks/Vt[buf^1]
    }

#pragma unroll
    for (int m = 0; m < 2; ++m) {
        const float inv = 1.0f / l_i[m];
        const int qi = i0 + rq0 + m * 16;
#pragma unroll
        for (int no = 0; no < 4; ++no) {
            ushort4 o;
            o.x = f2bfbits(Ov[m][no][0] * inv);
            o.y = f2bfbits(Ov[m][no][1] * inv);
            o.z = f2bfbits(Ov[m][no][2] * inv);
            o.w = f2bfbits(Ov[m][no][3] * inv);
            *(ushort4*)((unsigned short*)AO + (size_t)qi * D_MODEL + h * HEAD_DIM +
                        no * 16 + quad * 4) = o;
        }
    }
}

// ---------------------------------------------------------------------------
extern "C" void kernel_launch(void* const* d_in, const int* in_sizes, int n_in,
                              void* d_out, int out_size, void* d_ws, size_t ws_size,
                              hipStream_t stream) {
    const float* x  = (const float*)d_in[0];
    const float* Wq = (const float*)d_in[1];
    const float* Wk = (const float*)d_in[2];
    const float* Wv = (const float*)d_in[3];
    const float* Wo = (const float*)d_in[4];
    const float* bq = (const float*)d_in[5];
    const float* bk = (const float*)d_in[6];
    const float* bv = (const float*)d_in[7];
    const float* bo = (const float*)d_in[8];
    float* out = (float*)d_out;

    char* w = (char*)d_ws;
    const size_t MB = 1u << 20;
    __hip_bfloat16* xb    = (__hip_bfloat16*)(w + 0 * MB);   // 8 MB
    __hip_bfloat16* Wqkvt = (__hip_bfloat16*)(w + 8 * MB);   // 6 MB [3072][1024]
    __hip_bfloat16* Wot   = (__hip_bfloat16*)(w + 14 * MB);  // 2 MB
    float*          bcat  = (float*)(w + 16 * MB);           // 12 KB
    __hip_bfloat16* QKV   = (__hip_bfloat16*)(w + 17 * MB);  // 24 MB [4096][3072]
    __hip_bfloat16* AO    = (__hip_bfloat16*)(w + 41 * MB);  // 8 MB, end 49 MB

    prep_k<<<3073, 256, 0, stream>>>(x, Wq, Wk, Wv, Wo, bq, bk, bv,
                                     (unsigned short*)xb, Wqkvt, Wot, bcat);

    dim3 gqkv(QKV_LD / 128, S_LEN / 128);
    qkv_k<<<gqkv, 256, 0, stream>>>(xb, Wqkvt, bcat, QKV);

    dim3 ag(S_LEN / 128, N_HEADS);
    attn_k<<<ag, 256, 0, stream>>>(QKV, AO);

    dim3 go(D_MODEL / 128, S_LEN / 128);
    wo_k<<<go, 256, 0, stream>>>(AO, Wot, bo, out);
}

// Round 3
// 173.291 us; speedup vs baseline: 1.0237x; 1.0237x over previous
//
#include <hip/hip_runtime.h>
#include <hip/hip_bf16.h>

// ---------------------------------------------------------------------------
// LocalAttention R14:
//  - wo_k: REVERTED to 128x64 tile (512 blocks = 2 blocks/CU). R13's 128x128
//    gave 256 blocks = 1 block/CU -> barrier drains fully exposed (m114
//    overlap lost). Rule: keep 2-barrier GEMMs at >=2 blocks/CU.
//  - qkv_k + wo_k: BK 32 -> 64. Same load/MFMA totals, HALF the barrier
//    drains (the ~20% structural stall of this schedule). 128B LDS rows
//    would be 16-way bank conflict -> reuse R12's refcheck-verified XOR
//    swizzle (pre-swizzled global source + XOR'd ds_read col).
//  - attn_k: unchanged from R13 (dbuf K/V, T14 issue-early/write-late,
//    one barrier/iter, T5 setprio).
// Fixed: ~86us harness poison (2 fills/iter, 42-45us each, +-3us noise).
// ---------------------------------------------------------------------------

typedef __attribute__((ext_vector_type(8))) short bf16x8;
typedef __attribute__((ext_vector_type(4))) float f32x4;

#define S_LEN 4096
#define D_MODEL 1024
#define N_HEADS 16
#define HEAD_DIM 64
#define WINDOW 256
#define QKV_LD 3072

static __device__ __forceinline__ unsigned short f2bfbits(float f) {
    __hip_bfloat16 h = __float2bfloat16(f);
    unsigned short u;
    __builtin_memcpy(&u, &h, sizeof(u));
    return u;
}

typedef const __attribute__((address_space(1))) void c_gvoid;
typedef __attribute__((address_space(3))) void lvoid;
static __device__ __forceinline__ void gload16(const void* g, void* l) {
    __builtin_amdgcn_global_load_lds((c_gvoid*)g, (lvoid*)l, 16, 0, 0);
}

// ---------------- fused prep: x-cast, W transposes, bias concat (R8) --------
__global__ __launch_bounds__(256) void prep_k(const float* __restrict__ x,
                                              const float* __restrict__ Wq,
                                              const float* __restrict__ Wk,
                                              const float* __restrict__ Wv,
                                              const float* __restrict__ Wo,
                                              const float* __restrict__ bq,
                                              const float* __restrict__ bk,
                                              const float* __restrict__ bv,
                                              unsigned short* __restrict__ xb,
                                              __hip_bfloat16* __restrict__ Wqkvt,
                                              __hip_bfloat16* __restrict__ Wot,
                                              float* __restrict__ bias_cat) {
    const int b = blockIdx.x;
    const int t = threadIdx.x;
    if (b < 2048) {
        int i = b * 2048 + t * 8;
        float4 v0 = *(const float4*)(x + i);
        float4 v1 = *(const float4*)(x + i + 4);
        ushort4 o0, o1;
        o0.x = f2bfbits(v0.x); o0.y = f2bfbits(v0.y);
        o0.z = f2bfbits(v0.z); o0.w = f2bfbits(v0.w);
        o1.x = f2bfbits(v1.x); o1.y = f2bfbits(v1.y);
        o1.z = f2bfbits(v1.z); o1.w = f2bfbits(v1.w);
        *(ushort4*)(xb + i) = o0;
        *(ushort4*)(xb + i + 4) = o1;
        return;
    }
    if (b < 3072) {
        __shared__ __hip_bfloat16 tile[64][65];
        const int m = (b - 2048) >> 8;
        const int tid = (b - 2048) & 255;
        const int n0 = (tid & 15) * 64, k0 = (tid >> 4) * 64;
        const float* src = (m == 0) ? Wq : (m == 1) ? Wk : (m == 2) ? Wv : Wo;
        __hip_bfloat16* dst = (m < 3) ? (Wqkvt + (size_t)m * D_MODEL * D_MODEL) : Wot;
        for (int c = t; c < 1024; c += 256) {
            int r = c >> 4, c4 = (c & 15) * 4;
            float4 v = *(const float4*)(src + (size_t)(k0 + r) * D_MODEL + n0 + c4);
            tile[r][c4 + 0] = __float2bfloat16(v.x);
            tile[r][c4 + 1] = __float2bfloat16(v.y);
            tile[r][c4 + 2] = __float2bfloat16(v.z);
            tile[r][c4 + 3] = __float2bfloat16(v.w);
        }
        __syncthreads();
        for (int c = t; c < 1024; c += 256) {
            int rr = c >> 4, c4 = (c & 15) * 4;
            ushort4 o;
            unsigned short u0, u1, u2, u3;
            __builtin_memcpy(&u0, &tile[c4 + 0][rr], 2);
            __builtin_memcpy(&u1, &tile[c4 + 1][rr], 2);
            __builtin_memcpy(&u2, &tile[c4 + 2][rr], 2);
            __builtin_memcpy(&u3, &tile[c4 + 3][rr], 2);
            o.x = u0; o.y = u1; o.z = u2; o.w = u3;
            *(ushort4*)((unsigned short*)dst + (size_t)(n0 + rr) * D_MODEL + k0 + c4) = o;
        }
        return;
    }
    for (int c = t; c < 3 * D_MODEL; c += 256) {
        float v = (c < 1024) ? bq[c] : (c < 2048) ? bk[c - 1024] : bv[c - 2048];
        bias_cat[c] = v;
    }
}

// ---------------- QKV GEMM: 128x128, BK=64, XOR-swizzled LDS (R14) ----------
// C[4096][3072] = xb[4096][1024] * Wqkvt[3072][1024]^T + bcat.
// Staging/read swizzle algebra identical to R12's refcheck-verified qkv256.
__global__ __launch_bounds__(256) void qkv_k(const __hip_bfloat16* __restrict__ A,
                                             const __hip_bfloat16* __restrict__ Bt,
                                             const float* __restrict__ bias,
                                             __hip_bfloat16* __restrict__ Cout) {
    constexpr int K = D_MODEL, N = QKV_LD;
    __shared__ __align__(16) __hip_bfloat16 As[128 * 64];   // 16 KB
    __shared__ __align__(16) __hip_bfloat16 Bs[128 * 64];   // 16 KB

    const int m0 = blockIdx.y * 128, n0 = blockIdx.x * 128;
    const int t = threadIdx.x;
    const int wave = t >> 6, lane = t & 63;
    const int quad = lane >> 4, l16 = lane & 15;
    const int wm = (wave & 1) * 64, wn = (wave >> 1) * 64;

    // staging: row = c*32 + (t>>3); source col pre-swizzled by row&7
    const int srow = t >> 3;                               // 0..31
    const int scol = ((t & 7) ^ ((t >> 3) & 7)) * 8;       // swizzled source col

    f32x4 acc[4][4];
#pragma unroll
    for (int mi = 0; mi < 4; ++mi)
#pragma unroll
        for (int ni = 0; ni < 4; ++ni) acc[mi][ni] = (f32x4){0.f, 0.f, 0.f, 0.f};

    const __hip_bfloat16* gA = A + (size_t)(m0 + srow) * K + scol;
    const __hip_bfloat16* gB = Bt + (size_t)(n0 + srow) * K + scol;

    // read: byte col = ((quad ^ (row&7))<<4) ^ (kk<<6), row&7 == l16&7
    const int csw = ((quad ^ (l16 & 7)) << 4);

    for (int k0 = 0; k0 < K; k0 += 64) {
#pragma unroll
        for (int c = 0; c < 4; ++c) {
            gload16(gA + (size_t)(c * 32) * K + k0, &As[c * 2048 + t * 8]);
            gload16(gB + (size_t)(c * 32) * K + k0, &Bs[c * 2048 + t * 8]);
        }
        __syncthreads();

        bf16x8 af[4][2], bfr[4][2];
#pragma unroll
        for (int mi = 0; mi < 4; ++mi) {
            const char* pr = (const char*)As + (wm + mi * 16 + l16) * 128;
            af[mi][0] = *(const bf16x8*)(pr + csw);
            af[mi][1] = *(const bf16x8*)(pr + (csw ^ 64));
        }
#pragma unroll
        for (int ni = 0; ni < 4; ++ni) {
            const char* pr = (const char*)Bs + (wn + ni * 16 + l16) * 128;
            bfr[ni][0] = *(const bf16x8*)(pr + csw);
            bfr[ni][1] = *(const bf16x8*)(pr + (csw ^ 64));
        }
#pragma unroll
        for (int kk = 0; kk < 2; ++kk)
#pragma unroll
            for (int mi = 0; mi < 4; ++mi)
#pragma unroll
                for (int ni = 0; ni < 4; ++ni)
                    acc[mi][ni] = __builtin_amdgcn_mfma_f32_16x16x32_bf16(
                        af[mi][kk], bfr[ni][kk], acc[mi][ni], 0, 0, 0);
        __syncthreads();
    }

    // R2 epilogue: C row = quad*4+r, col = l16 (per 16x16 frag)
#pragma unroll
    for (int mi = 0; mi < 4; ++mi) {
#pragma unroll
        for (int ni = 0; ni < 4; ++ni) {
#pragma unroll
            for (int r = 0; r < 4; ++r) {
                int row = m0 + wm + mi * 16 + quad * 4 + r;
                int col = n0 + wn + ni * 16 + l16;
                float v = acc[mi][ni][r] + bias[col];
                Cout[(size_t)row * N + col] = __float2bfloat16(v);
            }
        }
    }
}

// ---------------- Wo GEMM: 128x64 swapped/float4, BK=64 swizzled (R14) ------
__global__ __launch_bounds__(256) void wo_k(const __hip_bfloat16* __restrict__ A,
                                            const __hip_bfloat16* __restrict__ Bt,
                                            const float* __restrict__ bias,
                                            float* __restrict__ Cout) {
    constexpr int TM = 128, TN = 64, K = D_MODEL, N = D_MODEL;
    constexpr int MI = 4, NI = 2;
    __shared__ __align__(16) __hip_bfloat16 As[TM * 64];   // 16 KB
    __shared__ __align__(16) __hip_bfloat16 Bs[TN * 64];   // 8 KB

    const int m0 = blockIdx.y * TM, n0 = blockIdx.x * TN;
    const int t = threadIdx.x;
    const int wave = t >> 6, lane = t & 63;
    const int quad = lane >> 4, l16 = lane & 15;
    const int wm = (wave & 1) * 64, wn = (wave >> 1) * 32;

    const int srow = t >> 3;
    const int scol = ((t & 7) ^ ((t >> 3) & 7)) * 8;

    f32x4 acc[MI][NI];
#pragma unroll
    for (int mi = 0; mi < MI; ++mi)
#pragma unroll
        for (int ni = 0; ni < NI; ++ni) acc[mi][ni] = (f32x4){0.f, 0.f, 0.f, 0.f};

    const __hip_bfloat16* gA = A + (size_t)(m0 + srow) * K + scol;
    const __hip_bfloat16* gB = Bt + (size_t)(n0 + srow) * K + scol;

    const int csw = ((quad ^ (l16 & 7)) << 4);

    for (int k0 = 0; k0 < K; k0 += 64) {
#pragma unroll
        for (int c = 0; c < 4; ++c)
            gload16(gA + (size_t)(c * 32) * K + k0, &As[c * 2048 + t * 8]);
#pragma unroll
        for (int c = 0; c < 2; ++c)
            gload16(gB + (size_t)(c * 32) * K + k0, &Bs[c * 2048 + t * 8]);
        __syncthreads();

        bf16x8 af[MI][2], bfr[NI][2];
#pragma unroll
        for (int mi = 0; mi < MI; ++mi) {
            const char* pr = (const char*)As + (wm + mi * 16 + l16) * 128;
            af[mi][0] = *(const bf16x8*)(pr + csw);
            af[mi][1] = *(const bf16x8*)(pr + (csw ^ 64));
        }
#pragma unroll
        for (int ni = 0; ni < NI; ++ni) {
            const char* pr = (const char*)Bs + (wn + ni * 16 + l16) * 128;
            bfr[ni][0] = *(const bf16x8*)(pr + csw);
            bfr[ni][1] = *(const bf16x8*)(pr + (csw ^ 64));
        }
#pragma unroll
        for (int kk = 0; kk < 2; ++kk)
#pragma unroll
            for (int mi = 0; mi < MI; ++mi)
#pragma unroll
                for (int ni = 0; ni < NI; ++ni)
                    acc[mi][ni] = __builtin_amdgcn_mfma_f32_16x16x32_bf16(
                        bfr[ni][kk], af[mi][kk], acc[mi][ni], 0, 0, 0);
        __syncthreads();
    }

    float4 bv[NI];
#pragma unroll
    for (int ni = 0; ni < NI; ++ni)
        bv[ni] = *(const float4*)&bias[n0 + wn + ni * 16 + quad * 4];
#pragma unroll
    for (int mi = 0; mi < MI; ++mi) {
        const int row = m0 + wm + mi * 16 + l16;
#pragma unroll
        for (int ni = 0; ni < NI; ++ni) {
            const int col = n0 + wn + ni * 16 + quad * 4;
            float4 o;
            o.x = acc[mi][ni][0] + bv[ni].x;
            o.y = acc[mi][ni][1] + bv[ni].y;
            o.z = acc[mi][ni][2] + bv[ni].z;
            o.w = acc[mi][ni][3] + bv[ni].w;
            *(float4*)(Cout + (size_t)row * N + col) = o;
        }
    }
}

// ---------------- sliding-window flash attention, 128-q blocks (R13) --------
// Double-buffered K/V, prefetch issued after QK^T (T14), one barrier/iter,
// setprio around MFMA clusters (T5). Numerics identical to R8 attn.
__global__ __launch_bounds__(256) void attn_k(const __hip_bfloat16* __restrict__ QKV,
                                              __hip_bfloat16* __restrict__ AO) {
    __shared__ __align__(16) __hip_bfloat16 Qs[128 * 64];     // 16 KB
    __shared__ __align__(16) __hip_bfloat16 Ks[2][64 * 64];   // 16 KB
    __shared__ __align__(16) __hip_bfloat16 Vt[2][64 * 72];   // 18 KB
    __shared__ __align__(16) __hip_bfloat16 Ps[128 * 72];     // 18 KB

    const int h = blockIdx.y;
    const int i0 = blockIdx.x * 128;
    const int t = threadIdx.x;
    const int wave = t >> 6, lane = t & 63;
    const int quad = lane >> 4, l16 = lane & 15;
    const float sc = 0.125f * 1.44269504088896f;  // 1/sqrt(64) * log2(e)

    const __hip_bfloat16* Q = QKV + h * HEAD_DIM;
    const __hip_bfloat16* K = QKV + D_MODEL + h * HEAD_DIM;
    const __hip_bfloat16* V = QKV + 2 * D_MODEL + h * HEAD_DIM;

    const int grow = t >> 3;                       // 0..31
    const int glog = ((t & 7) ^ ((t >> 3) & 7)) * 8;
    const int vp = t >> 3, vc = t & 7;

    const int tt0 = (i0 >= WINDOW) ? 0 : ((WINDOW - i0) >> 6);

    // ---- prologue: stage Q + first K/V tile (buf 0), single barrier --------
#pragma unroll
    for (int p = 0; p < 4; ++p)
        gload16(Q + (size_t)(i0 + p * 32 + grow) * QKV_LD + glog,
                &Qs[p * 2048 + t * 8]);
    {
        const int tb0 = i0 - WINDOW + tt0 * 64;
        uint4 pv0 = *(const uint4*)(V + (size_t)(tb0 + 2 * vp) * QKV_LD + vc * 8);
        uint4 pv1 = *(const uint4*)(V + (size_t)(tb0 + 2 * vp + 1) * QKV_LD + vc * 8);
#pragma unroll
        for (int p = 0; p < 2; ++p)
            gload16(K + (size_t)(tb0 + p * 32 + grow) * QKV_LD + glog,
                    &Ks[0][p * 2048 + t * 8]);
        const unsigned short* a0 = (const unsigned short*)&pv0;
        const unsigned short* a1 = (const unsigned short*)&pv1;
#pragma unroll
        for (int j = 0; j < 8; ++j) {
            unsigned int pk = (unsigned int)a0[j] | ((unsigned int)a1[j] << 16);
            *(unsigned int*)&Vt[0][(vc * 8 + j) * 72 + 2 * vp] = pk;
        }
    }
    __syncthreads();

    const int rq0 = wave * 32 + l16;     // lane's two q rows: rq0, rq0+16
    bf16x8 aq[2][2];
#pragma unroll
    for (int m = 0; m < 2; ++m) {
        const int rq = rq0 + m * 16;
#pragma unroll
        for (int kk = 0; kk < 2; ++kk)
            aq[m][kk] = *(const bf16x8*)&Qs[rq * 64 + ((kk * 4 + quad) ^ (rq & 7)) * 8];
    }

    float m_i[2] = {-3.0e38f, -3.0e38f}, l_i[2] = {0.f, 0.f};
    f32x4 Ov[2][4];
#pragma unroll
    for (int m = 0; m < 2; ++m)
#pragma unroll
        for (int no = 0; no < 4; ++no) Ov[m][no] = (f32x4){0.f, 0.f, 0.f, 0.f};

    for (int tt = tt0; tt < 6; ++tt) {
        const int tb = i0 - WINDOW + tt * 64;
        const int buf = (tt - tt0) & 1;

        // ---- QK^T on Ks[buf] ----
        f32x4 s[2][4];
#pragma unroll
        for (int m = 0; m < 2; ++m)
#pragma unroll
            for (int ni = 0; ni < 4; ++ni) s[m][ni] = (f32x4){0.f, 0.f, 0.f, 0.f};
        __builtin_amdgcn_s_setprio(1);
#pragma unroll
        for (int kk = 0; kk < 2; ++kk)
#pragma unroll
            for (int ni = 0; ni < 4; ++ni) {
                int rk = ni * 16 + l16;
                bf16x8 bk = *(const bf16x8*)&Ks[buf][rk * 64 + ((kk * 4 + quad) ^ (rk & 7)) * 8];
#pragma unroll
                for (int m = 0; m < 2; ++m)
                    s[m][ni] = __builtin_amdgcn_mfma_f32_16x16x32_bf16(
                        bk, aq[m][kk], s[m][ni], 0, 0, 0);
            }
        __builtin_amdgcn_s_setprio(0);

        // ---- prefetch next tile: V -> regs, K -> Ks[buf^1] (issue early) ---
        const bool pf = (tt < 5);
        uint4 nv0, nv1;
        if (pf) {
            const int tbn = tb + 64;
            nv0 = *(const uint4*)(V + (size_t)(tbn + 2 * vp) * QKV_LD + vc * 8);
            nv1 = *(const uint4*)(V + (size_t)(tbn + 2 * vp + 1) * QKV_LD + vc * 8);
#pragma unroll
            for (int p = 0; p < 2; ++p)
                gload16(K + (size_t)(tbn + p * 32 + grow) * QKV_LD + glog,
                        &Ks[buf ^ 1][p * 2048 + t * 8]);
        }

        // ---- softmax (unchanged numerics) ----
#pragma unroll
        for (int m = 0; m < 2; ++m) {
            const int qi = i0 + rq0 + m * 16;
            float mx = -3.0e38f;
#pragma unroll
            for (int ni = 0; ni < 4; ++ni)
#pragma unroll
                for (int r = 0; r < 4; ++r) {
                    int j = tb + ni * 16 + quad * 4 + r;
                    float v = s[m][ni][r] * sc;
                    bool ok = (j <= qi) && (qi - j < WINDOW);
                    v = ok ? v : -3.0e38f;
                    s[m][ni][r] = v;
                    mx = fmaxf(mx, v);
                }
            mx = fmaxf(mx, __shfl_xor(mx, 16));
            mx = fmaxf(mx, __shfl_xor(mx, 32));
            const float mn = fmaxf(m_i[m], mx);
            const float alpha = exp2f(m_i[m] - mn);
            m_i[m] = mn;
            float sum = 0.f;
#pragma unroll
            for (int ni = 0; ni < 4; ++ni)
#pragma unroll
                for (int r = 0; r < 4; ++r) {
                    float e = exp2f(s[m][ni][r] - mn);
                    s[m][ni][r] = e;
                    sum += e;
                }
            sum += __shfl_xor(sum, 16);
            sum += __shfl_xor(sum, 32);
            l_i[m] = l_i[m] * alpha + sum;
#pragma unroll
            for (int no = 0; no < 4; ++no) Ov[m][no] *= alpha;

            const int rq = rq0 + m * 16;
#pragma unroll
            for (int ni = 0; ni < 4; ++ni) {
                ushort4 w4;
                w4.x = f2bfbits(s[m][ni][0]); w4.y = f2bfbits(s[m][ni][1]);
                w4.z = f2bfbits(s[m][ni][2]); w4.w = f2bfbits(s[m][ni][3]);
                *(ushort4*)&Ps[rq * 72 + ni * 16 + quad * 4] = w4;
            }
        }

        // ---- PV on Vt[buf] ----
        __builtin_amdgcn_s_setprio(1);
#pragma unroll
        for (int kk = 0; kk < 2; ++kk) {
            bf16x8 ap[2];
#pragma unroll
            for (int m = 0; m < 2; ++m)
                ap[m] = *(const bf16x8*)&Ps[(rq0 + m * 16) * 72 + kk * 32 + quad * 8];
#pragma unroll
            for (int no = 0; no < 4; ++no) {
                bf16x8 bvv = *(const bf16x8*)&Vt[buf][(no * 16 + l16) * 72 + kk * 32 + quad * 8];
#pragma unroll
                for (int m = 0; m < 2; ++m)
                    Ov[m][no] = __builtin_amdgcn_mfma_f32_16x16x32_bf16(
                        bvv, ap[m], Ov[m][no], 0, 0, 0);
            }
        }
        __builtin_amdgcn_s_setprio(0);

        // ---- write prefetched V into Vt[buf^1] ----
        if (pf) {
            const unsigned short* a0 = (const unsigned short*)&nv0;
            const unsigned short* a1 = (const unsigned short*)&nv1;
#pragma unroll
            for (int j = 0; j < 8; ++j) {
                unsigned int pk = (unsigned int)a0[j] | ((unsigned int)a1[j] << 16);
                *(unsigned int*)&Vt[buf ^ 1][(vc * 8 + j) * 72 + 2 * vp] = pk;
            }
        }
        __syncthreads();  // drains K gload_lds; next iter reads Ks/Vt[buf^1]
    }

#pragma unroll
    for (int m = 0; m < 2; ++m) {
        const float inv = 1.0f / l_i[m];
        const int qi = i0 + rq0 + m * 16;
#pragma unroll
        for (int no = 0; no < 4; ++no) {
            ushort4 o;
            o.x = f2bfbits(Ov[m][no][0] * inv);
            o.y = f2bfbits(Ov[m][no][1] * inv);
            o.z = f2bfbits(Ov[m][no][2] * inv);
            o.w = f2bfbits(Ov[m][no][3] * inv);
            *(ushort4*)((unsigned short*)AO + (size_t)qi * D_MODEL + h * HEAD_DIM +
                        no * 16 + quad * 4) = o;
        }
    }
}

// ---------------------------------------------------------------------------
extern "C" void kernel_launch(void* const* d_in, const int* in_sizes, int n_in,
                              void* d_out, int out_size, void* d_ws, size_t ws_size,
                              hipStream_t stream) {
    const float* x  = (const float*)d_in[0];
    const float* Wq = (const float*)d_in[1];
    const float* Wk = (const float*)d_in[2];
    const float* Wv = (const float*)d_in[3];
    const float* Wo = (const float*)d_in[4];
    const float* bq = (const float*)d_in[5];
    const float* bk = (const float*)d_in[6];
    const float* bv = (const float*)d_in[7];
    const float* bo = (const float*)d_in[8];
    float* out = (float*)d_out;

    char* w = (char*)d_ws;
    const size_t MB = 1u << 20;
    __hip_bfloat16* xb    = (__hip_bfloat16*)(w + 0 * MB);   // 8 MB
    __hip_bfloat16* Wqkvt = (__hip_bfloat16*)(w + 8 * MB);   // 6 MB [3072][1024]
    __hip_bfloat16* Wot   = (__hip_bfloat16*)(w + 14 * MB);  // 2 MB
    float*          bcat  = (float*)(w + 16 * MB);           // 12 KB
    __hip_bfloat16* QKV   = (__hip_bfloat16*)(w + 17 * MB);  // 24 MB [4096][3072]
    __hip_bfloat16* AO    = (__hip_bfloat16*)(w + 41 * MB);  // 8 MB, end 49 MB

    prep_k<<<3073, 256, 0, stream>>>(x, Wq, Wk, Wv, Wo, bq, bk, bv,
                                     (unsigned short*)xb, Wqkvt, Wot, bcat);

    dim3 gqkv(QKV_LD / 128, S_LEN / 128);
    qkv_k<<<gqkv, 256, 0, stream>>>(xb, Wqkvt, bcat, QKV);

    dim3 ag(S_LEN / 128, N_HEADS);
    attn_k<<<ag, 256, 0, stream>>>(QKV, AO);

    dim3 go(D_MODEL / 64, S_LEN / 128);
    wo_k<<<go, 256, 0, stream>>>(AO, Wot, bo, out);
}

// Round 4
// 157.690 us; speedup vs baseline: 1.1249x; 1.0989x over previous
//
#include <hip/hip_runtime.h>
#include <hip/hip_bf16.h>

// ---------------------------------------------------------------------------
// LocalAttention R15:
//  - qkv_k + wo_k: minimum 2-phase pipeline (T3-min, m248v2 +10% @K=1024):
//    dbuf LDS; STAGE(buf^1, k+1) issued BEFORE the MFMA cluster; single
//    vmcnt(0)+s_barrier AFTER MFMAs -> load latency hides under compute.
//    (R14 evidence: halving barrier count at BK=64 was neutral -> the cost
//    is exposed latency per stage, not barrier count. m233 agrees.)
//  - qkv_k tile 128x128 -> 128x192: grid 16x32=512 blocks (2/CU), LDS
//    2x40KB=80KB (exactly 2 blocks/CU), 48 MFMA/wave per iter vs 32,
//    17% less staging bytes per MFMA.
//  - BK=64 XOR swizzle retained (refcheck-verified in R12+R14).
//  - attn_k/prep_k: unchanged (R13, verified twice).
// Race audit (1 barrier/iter): reads of buf[cur] retire via lgkmcnt(0)
// before barrier; writes to buf[cur] issue only after that barrier;
// vmcnt(0) before barrier completes buf[cur^1] for the next iter.
// ---------------------------------------------------------------------------

typedef __attribute__((ext_vector_type(8))) short bf16x8;
typedef __attribute__((ext_vector_type(4))) float f32x4;

#define S_LEN 4096
#define D_MODEL 1024
#define N_HEADS 16
#define HEAD_DIM 64
#define WINDOW 256
#define QKV_LD 3072

static __device__ __forceinline__ unsigned short f2bfbits(float f) {
    __hip_bfloat16 h = __float2bfloat16(f);
    unsigned short u;
    __builtin_memcpy(&u, &h, sizeof(u));
    return u;
}

typedef const __attribute__((address_space(1))) void c_gvoid;
typedef __attribute__((address_space(3))) void lvoid;
static __device__ __forceinline__ void gload16(const void* g, void* l) {
    __builtin_amdgcn_global_load_lds((c_gvoid*)g, (lvoid*)l, 16, 0, 0);
}

// ---------------- fused prep: x-cast, W transposes, bias concat (R8) --------
__global__ __launch_bounds__(256) void prep_k(const float* __restrict__ x,
                                              const float* __restrict__ Wq,
                                              const float* __restrict__ Wk,
                                              const float* __restrict__ Wv,
                                              const float* __restrict__ Wo,
                                              const float* __restrict__ bq,
                                              const float* __restrict__ bk,
                                              const float* __restrict__ bv,
                                              unsigned short* __restrict__ xb,
                                              __hip_bfloat16* __restrict__ Wqkvt,
                                              __hip_bfloat16* __restrict__ Wot,
                                              float* __restrict__ bias_cat) {
    const int b = blockIdx.x;
    const int t = threadIdx.x;
    if (b < 2048) {
        int i = b * 2048 + t * 8;
        float4 v0 = *(const float4*)(x + i);
        float4 v1 = *(const float4*)(x + i + 4);
        ushort4 o0, o1;
        o0.x = f2bfbits(v0.x); o0.y = f2bfbits(v0.y);
        o0.z = f2bfbits(v0.z); o0.w = f2bfbits(v0.w);
        o1.x = f2bfbits(v1.x); o1.y = f2bfbits(v1.y);
        o1.z = f2bfbits(v1.z); o1.w = f2bfbits(v1.w);
        *(ushort4*)(xb + i) = o0;
        *(ushort4*)(xb + i + 4) = o1;
        return;
    }
    if (b < 3072) {
        __shared__ __hip_bfloat16 tile[64][65];
        const int m = (b - 2048) >> 8;
        const int tid = (b - 2048) & 255;
        const int n0 = (tid & 15) * 64, k0 = (tid >> 4) * 64;
        const float* src = (m == 0) ? Wq : (m == 1) ? Wk : (m == 2) ? Wv : Wo;
        __hip_bfloat16* dst = (m < 3) ? (Wqkvt + (size_t)m * D_MODEL * D_MODEL) : Wot;
        for (int c = t; c < 1024; c += 256) {
            int r = c >> 4, c4 = (c & 15) * 4;
            float4 v = *(const float4*)(src + (size_t)(k0 + r) * D_MODEL + n0 + c4);
            tile[r][c4 + 0] = __float2bfloat16(v.x);
            tile[r][c4 + 1] = __float2bfloat16(v.y);
            tile[r][c4 + 2] = __float2bfloat16(v.z);
            tile[r][c4 + 3] = __float2bfloat16(v.w);
        }
        __syncthreads();
        for (int c = t; c < 1024; c += 256) {
            int rr = c >> 4, c4 = (c & 15) * 4;
            ushort4 o;
            unsigned short u0, u1, u2, u3;
            __builtin_memcpy(&u0, &tile[c4 + 0][rr], 2);
            __builtin_memcpy(&u1, &tile[c4 + 1][rr], 2);
            __builtin_memcpy(&u2, &tile[c4 + 2][rr], 2);
            __builtin_memcpy(&u3, &tile[c4 + 3][rr], 2);
            o.x = u0; o.y = u1; o.z = u2; o.w = u3;
            *(ushort4*)((unsigned short*)dst + (size_t)(n0 + rr) * D_MODEL + k0 + c4) = o;
        }
        return;
    }
    for (int c = t; c < 3 * D_MODEL; c += 256) {
        float v = (c < 1024) ? bq[c] : (c < 2048) ? bk[c - 1024] : bv[c - 2048];
        bias_cat[c] = v;
    }
}

// ---------------- QKV GEMM: 128x192, BK=64, 2-phase dbuf (R15) --------------
// C[4096][3072] = xb[4096][1024] * Wqkvt[3072][1024]^T + bcat.
__global__ __launch_bounds__(256, 2) void qkv_k(const __hip_bfloat16* __restrict__ A,
                                                const __hip_bfloat16* __restrict__ Bt,
                                                const float* __restrict__ bias,
                                                __hip_bfloat16* __restrict__ Cout) {
    constexpr int K = D_MODEL, N = QKV_LD;
    __shared__ __align__(16) char lds[2][40960];  // per buf: A 16KB | B 24KB

    const int m0 = blockIdx.y * 128, n0 = blockIdx.x * 192;
    const int t = threadIdx.x;
    const int wave = t >> 6, lane = t & 63;
    const int quad = lane >> 4, l16 = lane & 15;
    const int wm = (wave & 1) * 64, wn = (wave >> 1) * 96;

    const int srow = t >> 3;                          // 0..31
    const int scol = ((t & 7) ^ ((t >> 3) & 7)) * 8;  // swizzled source col

    f32x4 acc[4][6];
#pragma unroll
    for (int mi = 0; mi < 4; ++mi)
#pragma unroll
        for (int ni = 0; ni < 6; ++ni) acc[mi][ni] = (f32x4){0.f, 0.f, 0.f, 0.f};

    const __hip_bfloat16* gA = A + (size_t)(m0 + srow) * K + scol;
    const __hip_bfloat16* gB = Bt + (size_t)(n0 + srow) * K + scol;
    const int csw = ((quad ^ (l16 & 7)) << 4);

#define QSTAGE(WR, KT)                                                         \
    {                                                                          \
        const __hip_bfloat16* sa_ = gA + (KT) * 64;                            \
        const __hip_bfloat16* sb_ = gB + (KT) * 64;                            \
        char* da_ = &lds[WR][0] + t * 16;                                      \
        char* db_ = &lds[WR][16384] + t * 16;                                  \
        _Pragma("unroll") for (int p_ = 0; p_ < 4; ++p_)                       \
            gload16(sa_ + (size_t)(p_ * 32) * K, da_ + p_ * 4096);             \
        _Pragma("unroll") for (int p_ = 0; p_ < 6; ++p_)                       \
            gload16(sb_ + (size_t)(p_ * 32) * K, db_ + p_ * 4096);             \
    }

#define QITER(RD, WR, KT)                                                      \
    {                                                                          \
        bf16x8 af[4][2], bfr[6][2];                                            \
        const char* Ab_ = &lds[RD][0];                                         \
        const char* Bb_ = &lds[RD][16384];                                     \
        _Pragma("unroll") for (int mi = 0; mi < 4; ++mi) {                     \
            const char* pr = Ab_ + (wm + mi * 16 + l16) * 128;                 \
            af[mi][0] = *(const bf16x8*)(pr + csw);                            \
            af[mi][1] = *(const bf16x8*)(pr + (csw ^ 64));                     \
        }                                                                      \
        _Pragma("unroll") for (int ni = 0; ni < 6; ++ni) {                     \
            const char* pr = Bb_ + (wn + ni * 16 + l16) * 128;                 \
            bfr[ni][0] = *(const bf16x8*)(pr + csw);                           \
            bfr[ni][1] = *(const bf16x8*)(pr + (csw ^ 64));                    \
        }                                                                      \
        if ((KT) < 16) QSTAGE(WR, KT);                                         \
        asm volatile("s_waitcnt lgkmcnt(0)" ::: "memory");                     \
        __builtin_amdgcn_sched_barrier(0);                                     \
        __builtin_amdgcn_s_setprio(1);                                         \
        _Pragma("unroll") for (int kk = 0; kk < 2; ++kk)                       \
            _Pragma("unroll") for (int mi = 0; mi < 4; ++mi)                   \
                _Pragma("unroll") for (int ni = 0; ni < 6; ++ni)               \
                    acc[mi][ni] = __builtin_amdgcn_mfma_f32_16x16x32_bf16(     \
                        af[mi][kk], bfr[ni][kk], acc[mi][ni], 0, 0, 0);        \
        __builtin_amdgcn_s_setprio(0);                                         \
        __builtin_amdgcn_sched_barrier(0);                                     \
        asm volatile("s_waitcnt vmcnt(0)" ::: "memory");                       \
        __builtin_amdgcn_s_barrier();                                          \
    }

    QSTAGE(0, 0);
    asm volatile("s_waitcnt vmcnt(0)" ::: "memory");
    __builtin_amdgcn_s_barrier();

#pragma unroll 1
    for (int kt = 0; kt < 16; kt += 2) {
        QITER(0, 1, kt + 1);
        QITER(1, 0, kt + 2);
    }
#undef QITER
#undef QSTAGE

    // epilogue: C row = quad*4+r, col = l16 (per 16x16 frag)
#pragma unroll
    for (int mi = 0; mi < 4; ++mi) {
#pragma unroll
        for (int ni = 0; ni < 6; ++ni) {
#pragma unroll
            for (int r = 0; r < 4; ++r) {
                int row = m0 + wm + mi * 16 + quad * 4 + r;
                int col = n0 + wn + ni * 16 + l16;
                float v = acc[mi][ni][r] + bias[col];
                Cout[(size_t)row * N + col] = __float2bfloat16(v);
            }
        }
    }
}

// ---------------- Wo GEMM: 128x64 swapped/float4, BK=64, 2-phase (R15) ------
__global__ __launch_bounds__(256, 2) void wo_k(const __hip_bfloat16* __restrict__ A,
                                               const __hip_bfloat16* __restrict__ Bt,
                                               const float* __restrict__ bias,
                                               float* __restrict__ Cout) {
    constexpr int K = D_MODEL, N = D_MODEL;
    __shared__ __align__(16) char lds[2][24576];  // per buf: A 16KB | B 8KB

    const int m0 = blockIdx.y * 128, n0 = blockIdx.x * 64;
    const int t = threadIdx.x;
    const int wave = t >> 6, lane = t & 63;
    const int quad = lane >> 4, l16 = lane & 15;
    const int wm = (wave & 1) * 64, wn = (wave >> 1) * 32;

    const int srow = t >> 3;
    const int scol = ((t & 7) ^ ((t >> 3) & 7)) * 8;

    f32x4 acc[4][2];
#pragma unroll
    for (int mi = 0; mi < 4; ++mi)
#pragma unroll
        for (int ni = 0; ni < 2; ++ni) acc[mi][ni] = (f32x4){0.f, 0.f, 0.f, 0.f};

    const __hip_bfloat16* gA = A + (size_t)(m0 + srow) * K + scol;
    const __hip_bfloat16* gB = Bt + (size_t)(n0 + srow) * K + scol;
    const int csw = ((quad ^ (l16 & 7)) << 4);

#define WSTAGE(WR, KT)                                                         \
    {                                                                          \
        const __hip_bfloat16* sa_ = gA + (KT) * 64;                            \
        const __hip_bfloat16* sb_ = gB + (KT) * 64;                            \
        char* da_ = &lds[WR][0] + t * 16;                                      \
        char* db_ = &lds[WR][16384] + t * 16;                                  \
        _Pragma("unroll") for (int p_ = 0; p_ < 4; ++p_)                       \
            gload16(sa_ + (size_t)(p_ * 32) * K, da_ + p_ * 4096);             \
        _Pragma("unroll") for (int p_ = 0; p_ < 2; ++p_)                       \
            gload16(sb_ + (size_t)(p_ * 32) * K, db_ + p_ * 4096);             \
    }

#define WITER(RD, WR, KT)                                                      \
    {                                                                          \
        bf16x8 af[4][2], bfr[2][2];                                            \
        const char* Ab_ = &lds[RD][0];                                         \
        const char* Bb_ = &lds[RD][16384];                                     \
        _Pragma("unroll") for (int mi = 0; mi < 4; ++mi) {                     \
            const char* pr = Ab_ + (wm + mi * 16 + l16) * 128;                 \
            af[mi][0] = *(const bf16x8*)(pr + csw);                            \
            af[mi][1] = *(const bf16x8*)(pr + (csw ^ 64));                     \
        }                                                                      \
        _Pragma("unroll") for (int ni = 0; ni < 2; ++ni) {                     \
            const char* pr = Bb_ + (wn + ni * 16 + l16) * 128;                 \
            bfr[ni][0] = *(const bf16x8*)(pr + csw);                           \
            bfr[ni][1] = *(const bf16x8*)(pr + (csw ^ 64));                    \
        }                                                                      \
        if ((KT) < 16) WSTAGE(WR, KT);                                         \
        asm volatile("s_waitcnt lgkmcnt(0)" ::: "memory");                     \
        __builtin_amdgcn_sched_barrier(0);                                     \
        __builtin_amdgcn_s_setprio(1);                                         \
        _Pragma("unroll") for (int kk = 0; kk < 2; ++kk)                       \
            _Pragma("unroll") for (int mi = 0; mi < 4; ++mi)                   \
                _Pragma("unroll") for (int ni = 0; ni < 2; ++ni)               \
                    acc[mi][ni] = __builtin_amdgcn_mfma_f32_16x16x32_bf16(     \
                        bfr[ni][kk], af[mi][kk], acc[mi][ni], 0, 0, 0);        \
        __builtin_amdgcn_s_setprio(0);                                         \
        __builtin_amdgcn_sched_barrier(0);                                     \
        asm volatile("s_waitcnt vmcnt(0)" ::: "memory");                       \
        __builtin_amdgcn_s_barrier();                                          \
    }

    WSTAGE(0, 0);
    asm volatile("s_waitcnt vmcnt(0)" ::: "memory");
    __builtin_amdgcn_s_barrier();

#pragma unroll 1
    for (int kt = 0; kt < 16; kt += 2) {
        WITER(0, 1, kt + 1);
        WITER(1, 0, kt + 2);
    }
#undef WITER
#undef WSTAGE

    float4 bv[2];
#pragma unroll
    for (int ni = 0; ni < 2; ++ni)
        bv[ni] = *(const float4*)&bias[n0 + wn + ni * 16 + quad * 4];
#pragma unroll
    for (int mi = 0; mi < 4; ++mi) {
        const int row = m0 + wm + mi * 16 + l16;
#pragma unroll
        for (int ni = 0; ni < 2; ++ni) {
            const int col = n0 + wn + ni * 16 + quad * 4;
            float4 o;
            o.x = acc[mi][ni][0] + bv[ni].x;
            o.y = acc[mi][ni][1] + bv[ni].y;
            o.z = acc[mi][ni][2] + bv[ni].z;
            o.w = acc[mi][ni][3] + bv[ni].w;
            *(float4*)(Cout + (size_t)row * N + col) = o;
        }
    }
}

// ---------------- sliding-window flash attention, 128-q blocks (R13) --------
__global__ __launch_bounds__(256) void attn_k(const __hip_bfloat16* __restrict__ QKV,
                                              __hip_bfloat16* __restrict__ AO) {
    __shared__ __align__(16) __hip_bfloat16 Qs[128 * 64];     // 16 KB
    __shared__ __align__(16) __hip_bfloat16 Ks[2][64 * 64];   // 16 KB
    __shared__ __align__(16) __hip_bfloat16 Vt[2][64 * 72];   // 18 KB
    __shared__ __align__(16) __hip_bfloat16 Ps[128 * 72];     // 18 KB

    const int h = blockIdx.y;
    const int i0 = blockIdx.x * 128;
    const int t = threadIdx.x;
    const int wave = t >> 6, lane = t & 63;
    const int quad = lane >> 4, l16 = lane & 15;
    const float sc = 0.125f * 1.44269504088896f;  // 1/sqrt(64) * log2(e)

    const __hip_bfloat16* Q = QKV + h * HEAD_DIM;
    const __hip_bfloat16* K = QKV + D_MODEL + h * HEAD_DIM;
    const __hip_bfloat16* V = QKV + 2 * D_MODEL + h * HEAD_DIM;

    const int grow = t >> 3;                       // 0..31
    const int glog = ((t & 7) ^ ((t >> 3) & 7)) * 8;
    const int vp = t >> 3, vc = t & 7;

    const int tt0 = (i0 >= WINDOW) ? 0 : ((WINDOW - i0) >> 6);

    // ---- prologue: stage Q + first K/V tile (buf 0), single barrier --------
#pragma unroll
    for (int p = 0; p < 4; ++p)
        gload16(Q + (size_t)(i0 + p * 32 + grow) * QKV_LD + glog,
                &Qs[p * 2048 + t * 8]);
    {
        const int tb0 = i0 - WINDOW + tt0 * 64;
        uint4 pv0 = *(const uint4*)(V + (size_t)(tb0 + 2 * vp) * QKV_LD + vc * 8);
        uint4 pv1 = *(const uint4*)(V + (size_t)(tb0 + 2 * vp + 1) * QKV_LD + vc * 8);
#pragma unroll
        for (int p = 0; p < 2; ++p)
            gload16(K + (size_t)(tb0 + p * 32 + grow) * QKV_LD + glog,
                    &Ks[0][p * 2048 + t * 8]);
        const unsigned short* a0 = (const unsigned short*)&pv0;
        const unsigned short* a1 = (const unsigned short*)&pv1;
#pragma unroll
        for (int j = 0; j < 8; ++j) {
            unsigned int pk = (unsigned int)a0[j] | ((unsigned int)a1[j] << 16);
            *(unsigned int*)&Vt[0][(vc * 8 + j) * 72 + 2 * vp] = pk;
        }
    }
    __syncthreads();

    const int rq0 = wave * 32 + l16;     // lane's two q rows: rq0, rq0+16
    bf16x8 aq[2][2];
#pragma unroll
    for (int m = 0; m < 2; ++m) {
        const int rq = rq0 + m * 16;
#pragma unroll
        for (int kk = 0; kk < 2; ++kk)
            aq[m][kk] = *(const bf16x8*)&Qs[rq * 64 + ((kk * 4 + quad) ^ (rq & 7)) * 8];
    }

    float m_i[2] = {-3.0e38f, -3.0e38f}, l_i[2] = {0.f, 0.f};
    f32x4 Ov[2][4];
#pragma unroll
    for (int m = 0; m < 2; ++m)
#pragma unroll
        for (int no = 0; no < 4; ++no) Ov[m][no] = (f32x4){0.f, 0.f, 0.f, 0.f};

    for (int tt = tt0; tt < 6; ++tt) {
        const int tb = i0 - WINDOW + tt * 64;
        const int buf = (tt - tt0) & 1;

        // ---- QK^T on Ks[buf] ----
        f32x4 s[2][4];
#pragma unroll
        for (int m = 0; m < 2; ++m)
#pragma unroll
            for (int ni = 0; ni < 4; ++ni) s[m][ni] = (f32x4){0.f, 0.f, 0.f, 0.f};
        __builtin_amdgcn_s_setprio(1);
#pragma unroll
        for (int kk = 0; kk < 2; ++kk)
#pragma unroll
            for (int ni = 0; ni < 4; ++ni) {
                int rk = ni * 16 + l16;
                bf16x8 bk = *(const bf16x8*)&Ks[buf][rk * 64 + ((kk * 4 + quad) ^ (rk & 7)) * 8];
#pragma unroll
                for (int m = 0; m < 2; ++m)
                    s[m][ni] = __builtin_amdgcn_mfma_f32_16x16x32_bf16(
                        bk, aq[m][kk], s[m][ni], 0, 0, 0);
            }
        __builtin_amdgcn_s_setprio(0);

        // ---- prefetch next tile: V -> regs, K -> Ks[buf^1] (issue early) ---
        const bool pf = (tt < 5);
        uint4 nv0, nv1;
        if (pf) {
            const int tbn = tb + 64;
            nv0 = *(const uint4*)(V + (size_t)(tbn + 2 * vp) * QKV_LD + vc * 8);
            nv1 = *(const uint4*)(V + (size_t)(tbn + 2 * vp + 1) * QKV_LD + vc * 8);
#pragma unroll
            for (int p = 0; p < 2; ++p)
                gload16(K + (size_t)(tbn + p * 32 + grow) * QKV_LD + glog,
                        &Ks[buf ^ 1][p * 2048 + t * 8]);
        }

        // ---- softmax (unchanged numerics) ----
#pragma unroll
        for (int m = 0; m < 2; ++m) {
            const int qi = i0 + rq0 + m * 16;
            float mx = -3.0e38f;
#pragma unroll
            for (int ni = 0; ni < 4; ++ni)
#pragma unroll
                for (int r = 0; r < 4; ++r) {
                    int j = tb + ni * 16 + quad * 4 + r;
                    float v = s[m][ni][r] * sc;
                    bool ok = (j <= qi) && (qi - j < WINDOW);
                    v = ok ? v : -3.0e38f;
                    s[m][ni][r] = v;
                    mx = fmaxf(mx, v);
                }
            mx = fmaxf(mx, __shfl_xor(mx, 16));
            mx = fmaxf(mx, __shfl_xor(mx, 32));
            const float mn = fmaxf(m_i[m], mx);
            const float alpha = exp2f(m_i[m] - mn);
            m_i[m] = mn;
            float sum = 0.f;
#pragma unroll
            for (int ni = 0; ni < 4; ++ni)
#pragma unroll
                for (int r = 0; r < 4; ++r) {
                    float e = exp2f(s[m][ni][r] - mn);
                    s[m][ni][r] = e;
                    sum += e;
                }
            sum += __shfl_xor(sum, 16);
            sum += __shfl_xor(sum, 32);
            l_i[m] = l_i[m] * alpha + sum;
#pragma unroll
            for (int no = 0; no < 4; ++no) Ov[m][no] *= alpha;

            const int rq = rq0 + m * 16;
#pragma unroll
            for (int ni = 0; ni < 4; ++ni) {
                ushort4 w4;
                w4.x = f2bfbits(s[m][ni][0]); w4.y = f2bfbits(s[m][ni][1]);
                w4.z = f2bfbits(s[m][ni][2]); w4.w = f2bfbits(s[m][ni][3]);
                *(ushort4*)&Ps[rq * 72 + ni * 16 + quad * 4] = w4;
            }
        }

        // ---- PV on Vt[buf] ----
        __builtin_amdgcn_s_setprio(1);
#pragma unroll
        for (int kk = 0; kk < 2; ++kk) {
            bf16x8 ap[2];
#pragma unroll
            for (int m = 0; m < 2; ++m)
                ap[m] = *(const bf16x8*)&Ps[(rq0 + m * 16) * 72 + kk * 32 + quad * 8];
#pragma unroll
            for (int no = 0; no < 4; ++no) {
                bf16x8 bvv = *(const bf16x8*)&Vt[buf][(no * 16 + l16) * 72 + kk * 32 + quad * 8];
#pragma unroll
                for (int m = 0; m < 2; ++m)
                    Ov[m][no] = __builtin_amdgcn_mfma_f32_16x16x32_bf16(
                        bvv, ap[m], Ov[m][no], 0, 0, 0);
            }
        }
        __builtin_amdgcn_s_setprio(0);

        // ---- write prefetched V into Vt[buf^1] ----
        if (pf) {
            const unsigned short* a0 = (const unsigned short*)&nv0;
            const unsigned short* a1 = (const unsigned short*)&nv1;
#pragma unroll
            for (int j = 0; j < 8; ++j) {
                unsigned int pk = (unsigned int)a0[j] | ((unsigned int)a1[j] << 16);
                *(unsigned int*)&Vt[buf ^ 1][(vc * 8 + j) * 72 + 2 * vp] = pk;
            }
        }
        __syncthreads();  // drains K gload_lds; next iter reads Ks/Vt[buf^1]
    }

#pragma unroll
    for (int m = 0; m < 2; ++m) {
        const float inv = 1.0f / l_i[m];
        const int qi = i0 + rq0 + m * 16;
#pragma unroll
        for (int no = 0; no < 4; ++no) {
            ushort4 o;
            o.x = f2bfbits(Ov[m][no][0] * inv);
            o.y = f2bfbits(Ov[m][no][1] * inv);
            o.z = f2bfbits(Ov[m][no][2] * inv);
            o.w = f2bfbits(Ov[m][no][3] * inv);
            *(ushort4*)((unsigned short*)AO + (size_t)qi * D_MODEL + h * HEAD_DIM +
                        no * 16 + quad * 4) = o;
        }
    }
}

// ---------------------------------------------------------------------------
extern "C" void kernel_launch(void* const* d_in, const int* in_sizes, int n_in,
                              void* d_out, int out_size, void* d_ws, size_t ws_size,
                              hipStream_t stream) {
    const float* x  = (const float*)d_in[0];
    const float* Wq = (const float*)d_in[1];
    const float* Wk = (const float*)d_in[2];
    const float* Wv = (const float*)d_in[3];
    const float* Wo = (const float*)d_in[4];
    const float* bq = (const float*)d_in[5];
    const float* bk = (const float*)d_in[6];
    const float* bv = (const float*)d_in[7];
    const float* bo = (const float*)d_in[8];
    float* out = (float*)d_out;

    char* w = (char*)d_ws;
    const size_t MB = 1u << 20;
    __hip_bfloat16* xb    = (__hip_bfloat16*)(w + 0 * MB);   // 8 MB
    __hip_bfloat16* Wqkvt = (__hip_bfloat16*)(w + 8 * MB);   // 6 MB [3072][1024]
    __hip_bfloat16* Wot   = (__hip_bfloat16*)(w + 14 * MB);  // 2 MB
    float*          bcat  = (float*)(w + 16 * MB);           // 12 KB
    __hip_bfloat16* QKV   = (__hip_bfloat16*)(w + 17 * MB);  // 24 MB [4096][3072]
    __hip_bfloat16* AO    = (__hip_bfloat16*)(w + 41 * MB);  // 8 MB, end 49 MB

    prep_k<<<3073, 256, 0, stream>>>(x, Wq, Wk, Wv, Wo, bq, bk, bv,
                                     (unsigned short*)xb, Wqkvt, Wot, bcat);

    dim3 gqkv(QKV_LD / 192, S_LEN / 128);
    qkv_k<<<gqkv, 256, 0, stream>>>(xb, Wqkvt, bcat, QKV);

    dim3 ag(S_LEN / 128, N_HEADS);
    attn_k<<<ag, 256, 0, stream>>>(QKV, AO);

    dim3 go(D_MODEL / 64, S_LEN / 128);
    wo_k<<<go, 256, 0, stream>>>(AO, Wot, bo, out);
}